// Round 1
// baseline (488.170 us; speedup 1.0000x reference)
//
#include <hip/hip_runtime.h>
#include <math.h>

#define T_DIM 4096
#define D_DIM 1024
#define NUM_PAT 8
#define PAT_LEN 128
#define HALF_PAT 64

typedef __attribute__((ext_vector_type(4))) float f4;

struct BatchParams {
    float mean;
    float inv;
    int lo[NUM_PAT];
    int hi[NUM_PAT];
    int pad[14];   // pad to 128 B
};

// ---------------------------------------------------------------------------
// Kernel 1: per-row sum and sum-of-squares in fp64. One wave (64 lanes) per
// row of D=1024 floats; 4 waves per 256-thread block. Memory-bound (reads x,
// 256 MB). Normal (caching) loads on purpose: pulls x into L3 for kernel 3.
// Streams FORWARD (row 0..N-1) -> at completion L3 holds the tail of x.
// ---------------------------------------------------------------------------
__global__ __launch_bounds__(256) void row_reduce_kernel(
        const float* __restrict__ x,
        double* __restrict__ rowsum,
        double* __restrict__ rowsumsq,
        int nrows) {
    int wave = (int)((blockIdx.x * blockDim.x + threadIdx.x) >> 6);
    int lane = threadIdx.x & 63;
    if (wave >= nrows) return;
    const float4* xp = (const float4*)(x + (size_t)wave * D_DIM);
    float4 v[4];
#pragma unroll
    for (int q = 0; q < 4; ++q) v[q] = xp[lane + q * 64];   // 4 indep loads in flight
    double s1 = 0.0, s2 = 0.0;
#pragma unroll
    for (int q = 0; q < 4; ++q) {
        double a = (double)v[q].x, b = (double)v[q].y;
        double c = (double)v[q].z, d = (double)v[q].w;
        s1 += (a + b) + (c + d);
        s2 += (a * a + b * b) + (c * c + d * d);
    }
#pragma unroll
    for (int off = 32; off >= 1; off >>= 1) {
        s1 += __shfl_down(s1, off, 64);
        s2 += __shfl_down(s2, off, 64);
    }
    if (lane == 0) {
        rowsum[wave] = s1;
        rowsumsq[wave] = s2;
    }
}

// ---------------------------------------------------------------------------
// (v,i) total order matching jax.lax.top_k: value descending, ties -> lower
// index wins. All elements have distinct i, so this is a strict total order.
// ---------------------------------------------------------------------------
__device__ __forceinline__ bool better(float va, int ia, float vb, int ib) {
    return (va > vb) || (va == vb && ia < ib);
}

// ---------------------------------------------------------------------------
// Kernel 2: one 256-thread block per batch.
//  - xt (fp32) from rowsum; peak mask (local max over 3-window, -inf borders)
//  - top-8: per-thread sorted top-8 (insertion over its 16 stride-256
//    candidates; the global top-8 is contained in the union of per-thread
//    top-8s), then an 8-level merge tree in LDS. Each merge = bitonic
//    half-cleaner (m[q] = better(A[q], B[7-q]) holds the top-8 of A∪B) +
//    3-stage bitonic clean (distances 4,2,1) to restore descending order.
//    All register indices compile-time (no scratch). Barriers: ~11 vs the
//    ~72 of the previous iterative-argmax version.
//  - window-gathered mean / unbiased std via rowsum/rowsumsq (fp64),
//    wave-shuffle reduction (no LDS tree barriers).
// ---------------------------------------------------------------------------
__global__ __launch_bounds__(256) void select_kernel(
        const double* __restrict__ rowsum,
        const double* __restrict__ rowsumsq,
        BatchParams* __restrict__ params) {
    int b = blockIdx.x;
    int j = threadIdx.x;
    __shared__ float xs[T_DIM];
    __shared__ float sv[256 * 8];
    __shared__ int   si[256 * 8];
    __shared__ int   ind[NUM_PAT];
    __shared__ double w1[4], w2[4];

    const double* rs = rowsum   + (size_t)b * T_DIM;
    const double* rq = rowsumsq + (size_t)b * T_DIM;

    for (int t = j; t < T_DIM; t += 256) xs[t] = (float)rs[t];
    __syncthreads();

    // --- per-thread sorted top-8 over 16 stride-256 candidates ------------
    float lv[8]; int li[8];
#pragma unroll
    for (int q = 0; q < 8; ++q) { lv[q] = -INFINITY; li[q] = 0x7fffffff; }
#pragma unroll
    for (int q = 0; q < 16; ++q) {
        int t = j + q * 256;
        float c = xs[t];
        float l = (t > 0)         ? xs[t - 1] : -INFINITY;
        float r = (t < T_DIM - 1) ? xs[t + 1] : -INFINITY;
        float v = (c >= l && c >= r) ? c : 0.0f;   // local peak else 0
        if (better(v, t, lv[7], li[7])) {
            lv[7] = v; li[7] = t;
#pragma unroll
            for (int p = 7; p > 0; --p) {
                if (better(lv[p], li[p], lv[p - 1], li[p - 1])) {
                    float tv = lv[p]; lv[p] = lv[p - 1]; lv[p - 1] = tv;
                    int   ti = li[p]; li[p] = li[p - 1]; li[p - 1] = ti;
                }
            }
        }
    }

    // --- merge tree: 256 sorted lists -> 1 -------------------------------
#pragma unroll
    for (int q = 0; q < 8; ++q) { sv[(j << 3) + q] = lv[q]; si[(j << 3) + q] = li[q]; }
    __syncthreads();
    for (int s = 128; s >= 1; s >>= 1) {
        if (j < s) {
            float ov[8]; int oi[8];
#pragma unroll
            for (int q = 0; q < 8; ++q) {
                ov[q] = sv[((j + s) << 3) + q];
                oi[q] = si[((j + s) << 3) + q];
            }
            float mv[8]; int mi[8];
#pragma unroll
            for (int q = 0; q < 8; ++q) {     // half-cleaner: top-8 of union
                if (better(lv[q], li[q], ov[7 - q], oi[7 - q])) {
                    mv[q] = lv[q]; mi[q] = li[q];
                } else {
                    mv[q] = ov[7 - q]; mi[q] = oi[7 - q];
                }
            }
#define CE(a, b_) { if (better(mv[b_], mi[b_], mv[a], mi[a])) { \
                float tv = mv[a]; mv[a] = mv[b_]; mv[b_] = tv;  \
                int   ti = mi[a]; mi[a] = mi[b_]; mi[b_] = ti; } }
            CE(0, 4) CE(1, 5) CE(2, 6) CE(3, 7)   // bitonic clean: dist 4
            CE(0, 2) CE(1, 3) CE(4, 6) CE(5, 7)   // dist 2
            CE(0, 1) CE(2, 3) CE(4, 5) CE(6, 7)   // dist 1
#undef CE
#pragma unroll
            for (int q = 0; q < 8; ++q) {
                lv[q] = mv[q]; li[q] = mi[q];
                sv[(j << 3) + q] = mv[q]; si[(j << 3) + q] = mi[q];
            }
        }
        __syncthreads();
    }
    if (j == 0) {
#pragma unroll
        for (int k = 0; k < NUM_PAT; ++k) ind[k] = li[k];
    }
    __syncthreads();

    // --- gather-window sums over M = 8*128 (clipped, possibly dup) rows ---
    double s1 = 0.0, s2 = 0.0;
#pragma unroll
    for (int mq = 0; mq < 4; ++mq) {
        int m = j + mq * 256;
        int k = m >> 7;
        int t = ind[k] + (m & (PAT_LEN - 1)) - HALF_PAT;
        t = min(max(t, 0), T_DIM - 1);
        s1 += rs[t];
        s2 += rq[t];
    }
#pragma unroll
    for (int off = 32; off >= 1; off >>= 1) {
        s1 += __shfl_down(s1, off, 64);
        s2 += __shfl_down(s2, off, 64);
    }
    if ((j & 63) == 0) { w1[j >> 6] = s1; w2[j >> 6] = s2; }
    __syncthreads();
    if (j == 0) {
        double S1 = (w1[0] + w1[1]) + (w1[2] + w1[3]);
        double S2 = (w2[0] + w2[1]) + (w2[2] + w2[3]);
        const double N = (double)(NUM_PAT * PAT_LEN) * (double)D_DIM;
        double mean = S1 / N;
        double var  = (S2 - S1 * S1 / N) / (N - 1.0);
        if (var < 0.0) var = 0.0;
        float stdf = (float)sqrt(var);
        params[b].mean = (float)mean;
        params[b].inv  = 1.0f / (stdf + 1e-8f);
#pragma unroll
        for (int k = 0; k < NUM_PAT; ++k) {
            params[b].lo[k] = max(0, ind[k] - HALF_PAT);
            params[b].hi[k] = min(T_DIM - 1, ind[k] + HALF_PAT - 1);
        }
    }
}

// ---------------------------------------------------------------------------
// Kernel 3: elementwise apply. 4 rows per 256-thread block, one wave per row
// (mask & params wave-uniform -> zero divergence). Non-temporal stores keep
// `out` from evicting x in L2/L3.
// REVERSE row traversal: kernel 1 streamed x forward, so L3 (256 MB = |x|)
// holds the TAIL of x. Forward re-read is the just-fits-LRU thrash pattern
// (~0% hits: each line needed is the one most recently evicted). Reading
// row N-1 -> 0 starts on resident lines and stays behind the eviction
// frontier, converting most of the 256 MB re-fetch into L3 hits.
// ---------------------------------------------------------------------------
__global__ __launch_bounds__(256) void apply_kernel(
        const float* __restrict__ x,
        const float* __restrict__ gamma,
        const float* __restrict__ beta,
        const BatchParams* __restrict__ params,
        float* __restrict__ out) {
    int rb   = (int)(gridDim.x - 1 - blockIdx.x);       // reversed block order
    int row  = (rb << 2) + (threadIdx.x >> 6);          // 4 rows/block
    int lane = threadIdx.x & 63;
    int b = row >> 12;                                  // T = 4096 rows/batch
    int t = row & (T_DIM - 1);
    const BatchParams* P = params + b;
    bool covered = false;
#pragma unroll
    for (int k = 0; k < NUM_PAT; ++k)
        covered |= (t >= P->lo[k] && t <= P->hi[k]);
    float mask = covered ? (float)0.8807970779778823 : (float)0.04742587317756678;
    float mean = P->mean;
    float inv  = P->inv;

    size_t base = (size_t)row * D_DIM;
    const float4* xp = (const float4*)(x + base);
    float4*       op = (float4*)(out + base);
    const float4* gp = (const float4*)gamma;
    const float4* bp = (const float4*)beta;

    float4 xv[4], g[4], bt[4];
#pragma unroll
    for (int q = 0; q < 4; ++q) {
        int c4 = lane + q * 64;
        xv[q] = xp[c4];
        g[q]  = gp[c4];
        bt[q] = bp[c4];
    }
#pragma unroll
    for (int q = 0; q < 4; ++q) {
        f4 o;
        o.x = (g[q].x * ((xv[q].x - mean) * inv) + bt[q].x) * mask;
        o.y = (g[q].y * ((xv[q].y - mean) * inv) + bt[q].y) * mask;
        o.z = (g[q].z * ((xv[q].z - mean) * inv) + bt[q].z) * mask;
        o.w = (g[q].w * ((xv[q].w - mean) * inv) + bt[q].w) * mask;
        __builtin_nontemporal_store(o, (f4*)(op + lane + q * 64));
    }
}

// ---------------------------------------------------------------------------
extern "C" void kernel_launch(void* const* d_in, const int* in_sizes, int n_in,
                              void* d_out, int out_size, void* d_ws, size_t ws_size,
                              hipStream_t stream) {
    const float* x     = (const float*)d_in[0];
    const float* gamma = (const float*)d_in[1];
    const float* beta  = (const float*)d_in[2];
    float* out = (float*)d_out;

    int total = in_sizes[0];
    int B = total / (T_DIM * D_DIM);
    int nrows = B * T_DIM;

    double* rowsum   = (double*)d_ws;
    double* rowsumsq = rowsum + nrows;
    BatchParams* params =
        (BatchParams*)((char*)d_ws + 2 * (size_t)nrows * sizeof(double));

    row_reduce_kernel<<<(nrows + 3) / 4, 256, 0, stream>>>(x, rowsum, rowsumsq, nrows);
    select_kernel<<<B, 256, 0, stream>>>(rowsum, rowsumsq, params);
    apply_kernel<<<nrows / 4, 256, 0, stream>>>(x, gamma, beta, params, out);
}